// Round 15
// baseline (400.260 us; speedup 1.0000x reference)
//
#include <hip/hip_runtime.h>
#include <hip/hip_bf16.h>

#define NB 192
#define DD 128
#define RR 32
#define RBS 40    // padded Rb row stride (ushorts)

typedef __attribute__((ext_vector_type(8))) short bf16x8;
typedef __attribute__((ext_vector_type(4))) float f32x4;

template<int M> struct IC { static constexpr int value = M; };

__device__ __forceinline__ unsigned short f2bf(float x) {
  union { __hip_bfloat16 h; unsigned short u; } c;
  c.h = __float2bfloat16(x);
  return c.u;
}
__device__ __forceinline__ unsigned int pack2bf(float a, float b) {
  union { unsigned short u[2]; unsigned int w; } r;
  r.u[0] = f2bf(a); r.u[1] = f2bf(b); return r.w;
}

// ---------------- weight fragment prep (runs every call) ----------------
__global__ __launch_bounds__(256) void cg_prep(
    const float* __restrict__ Ws1, const float* __restrict__ Wd1,
    const float* __restrict__ Wv1, const float* __restrict__ Wt1,
    const float* __restrict__ Ws2, const float* __restrict__ Wd2,
    const float* __restrict__ Wv2, const float* __restrict__ Wt2,
    const float* __restrict__ bs1, const float* __restrict__ bd1,
    const float* __restrict__ bv1, const float* __restrict__ bt1,
    const float* __restrict__ bs2, const float* __restrict__ bd2,
    const float* __restrict__ bv2, const float* __restrict__ bt2,
    unsigned short* __restrict__ w1f, unsigned short* __restrict__ w2f,
    float* __restrict__ bcat1, float* __restrict__ bcat2)
{
  const float* W1s[4] = {Ws1, Wd1, Wv1, Wt1};
  const float* W2s[4] = {Ws2, Wd2, Wv2, Wt2};
  const float* B1s[4] = {bs1, bd1, bv1, bt1};
  const float* B2s[4] = {bs2, bd2, bv2, bt2};
  int t = blockIdx.x * 256 + threadIdx.x;
  if (t < 2048) {
    int lane = t & 63, f = t >> 6;
    int mlp = f >> 3, htl = f & 7;
    int g = lane >> 4, ln = lane & 15;
    const float* W = W1s[mlp];
    union { unsigned short u[8]; uint4 d; } p;
    #pragma unroll
    for (int e = 0; e < 8; ++e)
      p.u[e] = f2bf(W[(8*g + e) * DD + htl*16 + ln]);
    *(uint4*)&w1f[t * 8] = p.d;
  } else if (t < 10240) {
    int t2 = t - 2048;
    int lane = t2 & 63, f = t2 >> 6;    // f = (mlp*4+ks)*8 + ct
    int ct = f & 7, ks = (f >> 3) & 3, mlp = f >> 5;
    int g = lane >> 4, ln = lane & 15;
    const float* W = W2s[mlp];
    union { unsigned short u[8]; uint4 d; } p;
    #pragma unroll
    for (int e = 0; e < 8; ++e)
      p.u[e] = f2bf(W[(32*ks + 8*g + e) * DD + ct*16 + ln]);
    *(uint4*)&w2f[t2 * 8] = p.d;
  } else if (t < 10752) {
    int t3 = t - 10240;
    bcat1[t3] = B1s[t3 >> 7][t3 & 127];
  } else if (t < 11264) {
    int t3 = t - 10752;
    bcat2[t3] = B2s[t3 >> 7][t3 & 127];
  }
}

// ---------------- main kernel ------------------------------------------
// JBLK=64; 4 MLP passes software-pipelined on a double-buffered Hu
// (4 barriers in the pass chain); atomic per-bi partial accumulation;
// last-arriving j-block runs the LN/Wo epilogue inline (fused cg_final).
__global__ __launch_bounds__(256, 3) void cg_main(
    const float* __restrict__ node_s, const float* __restrict__ node_v,
    const float* __restrict__ rbf, const float* __restrict__ r_hat,
    const float* __restrict__ mask,
    const unsigned short* __restrict__ w1f, const unsigned short* __restrict__ w2f,
    const float* __restrict__ bcat1, const float* __restrict__ bcat2,
    const float* __restrict__ ln_g, const float* __restrict__ ln_b,
    const float* __restrict__ Wo, const float* __restrict__ bo,
    const float* __restrict__ v_scale, const float* __restrict__ t_scale,
    float* __restrict__ ws, unsigned int* __restrict__ cnt,
    float* __restrict__ out)
{
  constexpr int JBLK   = 64;
  constexpr int NSPLIT = NB / JBLK;   // 3
  constexpr int NT     = 4;           // j-tiles of 16
  constexpr int KSL    = 2;           // 32-j slices for Y-MFMA
  __shared__ __align__(16) char smem[49152];
  __shared__ unsigned int lastFlag;
  unsigned short* Rb  = (unsigned short*)smem;             // 64*40*2  = 5120
  unsigned short* Hu0 = (unsigned short*)(smem + 5120);    // 64*128*2 = 16384
  unsigned short* Hu1 = (unsigned short*)(smem + 21504);   // 64*128*2 = 16384
  float*          YYf = (float*)(smem + 37888);            // 12*64*4  = 3072
  // YYf planes: 0 m^2 | 1-3 m*Y1 | 4-6 m^2*Y1 | 7-11 m^2*Y2

  const int tid  = threadIdx.x;
  const int bx   = blockIdx.x;
  const int bi   = bx / NSPLIT;
  const int jq   = bx % NSPLIT;
  const int j0   = jq * JBLK;
  const int b    = bi / NB;
  const int wid  = tid >> 6;
  const int lane = tid & 63;
  const int g = lane >> 4, ln = lane & 15;

  auto haddr = [](int j, int hb) {      // hb = byte col in 256B Hu row
    return j * 128 + (((hb) ^ ((j & 7) << 4)) >> 1);
  };

  const float* nsb = node_s + (size_t)b * (NB * DD);
  const f32x4 zacc = {0.f, 0.f, 0.f, 0.f};
  const int c0 = wid * 32 + ln, c1 = c0 + 16;

  // ---- node_s rows this thread needs -> registers (issued first, used late) ----
  float nsr[4][4][2];
  {
    const float* nsp = nsb + (size_t)j0 * DD;
    #pragma unroll
    for (int mt = 0; mt < 4; ++mt)
      #pragma unroll
      for (int r = 0; r < 4; ++r) {
        int jl = mt * 16 + 4 * g + r;
        nsr[mt][r][0] = nsp[(size_t)jl * DD + c0];
        nsr[mt][r][1] = nsp[(size_t)jl * DD + c1];
      }
  }

  // ---- stage rbf -> Rb (bf16, padded stride) ----
  {
    const float4* rrow = (const float4*)(rbf + (size_t)bi * (NB * RR) + j0 * RR);
    #pragma unroll
    for (int f = tid; f < JBLK * 8; f += 256) {
      float4 v = rrow[f];
      union { unsigned short u[4]; uint2 d; } p;
      p.u[0] = f2bf(v.x); p.u[1] = f2bf(v.y); p.u[2] = f2bf(v.z); p.u[3] = f2bf(v.w);
      *(uint2*)&Rb[(f >> 3) * RBS + (f & 7) * 4] = p.d;
    }
  }
  // ---- Y tables (f32, 12 planes, m^2 folded; 3 planes per wave) ----
  {
    int j = tid & 63, grp = tid >> 6;
    int jj = j0 + j;
    const float* rh = r_hat + ((size_t)bi * NB + jj) * 3;
    float x = rh[0], y = rh[1], z = rh[2];
    float m = mask[(size_t)bi * NB + jj];
    float inv = 1.0f / (sqrtf(x*x + y*y + z*z) + 1e-12f);
    x *= inv; y *= inv; z *= inv;
    float m2 = m * m;
    float v0, v1, v2;
    if (grp == 0)      { v0 = m2;
                         v1 = 0.48860252f * m * x;
                         v2 = 0.48860252f * m * y; }
    else if (grp == 1) { v0 = 0.48860252f * m * z;
                         v1 = 0.48860252f * m2 * x;
                         v2 = 0.48860252f * m2 * y; }
    else if (grp == 2) { v0 = 0.48860252f * m2 * z;
                         v1 = 1.09254843f * m2 * x * y;
                         v2 = 1.09254843f * m2 * y * z; }
    else               { v0 = 0.31539157f * m2 * (3.f * z * z - 1.f);
                         v1 = 1.09254843f * m2 * x * z;
                         v2 = 0.54627422f * m2 * (x*x - y*y); }
    YYf[(grp*3 + 0) * JBLK + j] = v0;
    YYf[(grp*3 + 1) * JBLK + j] = v1;
    YYf[(grp*3 + 2) * JBLK + j] = v2;
  }
  __syncthreads();

  // ---- build Y A-fragments into Hu0 tail region is NOT possible; YA lives
  //      in registers per use; staged build (R13): use Hu1 as temp? No —
  //      keep R13's dedicated YA via the YYf+YA trick: YA goes where R13 put
  //      it (it had 8KB at 40960). Here we keep the R13 layout exactly:
  __shared__ __align__(16) unsigned short YA[4 * KSL * 64 * 8];  // 8192 B
  for (int s = tid; s < 4 * KSL * 64; s += 256) {
    int lane_l = s & 63, rest = s >> 6;
    int ksl = rest % KSL, m = rest / KSL;
    int gl = lane_l >> 4, lnl = lane_l & 15;
    int jb0 = 32*ksl + 4*gl;
    union { unsigned short u[8]; uint4 d; } P;
    bool ok = (m == 0 && lnl == 0) ||
              (m == 1 && lnl >= 1 && lnl <= 3) ||
              (m == 2 && lnl >= 4 && lnl <= 6) ||
              (m == 3 && lnl >= 7 && lnl <= 11);
    if (ok) {
      const float* pl = YYf + lnl * JBLK;
      float4 a = *(const float4*)(pl + jb0);
      float4 c = *(const float4*)(pl + jb0 + 16);
      P.u[0]=f2bf(a.x); P.u[1]=f2bf(a.y); P.u[2]=f2bf(a.z); P.u[3]=f2bf(a.w);
      P.u[4]=f2bf(c.x); P.u[5]=f2bf(c.y); P.u[6]=f2bf(c.z); P.u[7]=f2bf(c.w);
    } else {
      #pragma unroll
      for (int e = 0; e < 8; ++e) P.u[e] = 0;
    }
    *(uint4*)&YA[s * 8] = P.d;
  }
  __syncthreads();

  f32x4 accY0 = zacc, accY1 = zacc;   // rows = planes 0..11, cols = c0 / c1

  // ---- GEMM1 for one mode into the given Hu buffer ----
  auto g1 = [&](auto MC, unsigned short* Hu) {
    constexpr int MODE = decltype(MC)::value;
    #pragma unroll
    for (int q = 0; q < 2; ++q) {
      const int htl = wid * 2 + q;
      const int f   = MODE * 8 + htl;
      bf16x8 a1 = *(const bf16x8*)&w1f[(f * 64 + lane) * 8];
      float4 b1v = *(const float4*)(bcat1 + MODE * DD + htl*16 + 4*g);
      #pragma unroll
      for (int nt = 0; nt < NT; ++nt) {
        int j = nt * 16 + ln;
        bf16x8 bb = *(const bf16x8*)&Rb[j * RBS + 8 * g];
        f32x4 h4 = __builtin_amdgcn_mfma_f32_16x16x32_bf16(a1, bb, zacc, 0, 0, 0);
        union { unsigned short u[4]; uint2 d; } hp;
        float x0 = h4[0] + b1v.x; hp.u[0] = f2bf(x0 * __builtin_amdgcn_rcpf(1.f + __expf(-x0)));
        float x1 = h4[1] + b1v.y; hp.u[1] = f2bf(x1 * __builtin_amdgcn_rcpf(1.f + __expf(-x1)));
        float x2 = h4[2] + b1v.z; hp.u[2] = f2bf(x2 * __builtin_amdgcn_rcpf(1.f + __expf(-x2)));
        float x3 = h4[3] + b1v.w; hp.u[3] = f2bf(x3 * __builtin_amdgcn_rcpf(1.f + __expf(-x3)));
        *(uint2*)&Hu[haddr(j, htl*32 + 8*g)] = hp.d;
      }
    }
  };

  // ---- GEMM2 + epilogue + Y-MFMA for one mode from the given Hu buffer ----
  auto g2 = [&](auto MC, const unsigned short* Hu) {
    constexpr int MODE = decltype(MC)::value;
    bf16x8 Bf[4][2];
    #pragma unroll
    for (int ks = 0; ks < 4; ++ks)
      #pragma unroll
      for (int t = 0; t < 2; ++t)
        Bf[ks][t] = *(const bf16x8*)&w2f[(((MODE*4 + ks)*8 + 2*wid + t) * 64 + lane) * 8];
    float b2c0 = bcat2[MODE * DD + c0], b2c1 = bcat2[MODE * DD + c1];
    unsigned int pw[2][NT][2];
    #pragma unroll
    for (int mt = 0; mt < NT; ++mt) {
      f32x4 acc0 = zacc, acc1 = zacc;
      #pragma unroll
      for (int ks = 0; ks < 4; ++ks) {
        bf16x8 a = *(const bf16x8*)&Hu[haddr(mt*16 + ln, ks*64 + 16*g)];
        acc0 = __builtin_amdgcn_mfma_f32_16x16x32_bf16(a, Bf[ks][0], acc0, 0, 0, 0);
        acc1 = __builtin_amdgcn_mfma_f32_16x16x32_bf16(a, Bf[ks][1], acc1, 0, 0, 0);
      }
      #pragma unroll
      for (int wd = 0; wd < 2; ++wd) {
        float w00 = acc0[2*wd] + b2c0, w01 = acc0[2*wd+1] + b2c0;
        float w10 = acc1[2*wd] + b2c1, w11 = acc1[2*wd+1] + b2c1;
        float p00, p01, p10, p11;
        if constexpr (MODE == 1) {
          p00 = w00; p01 = w01; p10 = w10; p11 = w11;
        } else {
          p00 = nsr[mt][2*wd+0][0] * w00;
          p01 = nsr[mt][2*wd+1][0] * w01;
          p10 = nsr[mt][2*wd+0][1] * w10;
          p11 = nsr[mt][2*wd+1][1] * w11;
        }
        pw[0][mt][wd] = pack2bf(p00, p01);
        pw[1][mt][wd] = pack2bf(p10, p11);
      }
    }
    #pragma unroll
    for (int ksl = 0; ksl < KSL; ++ksl) {
      bf16x8 ya = *(const bf16x8*)&YA[((MODE*KSL + ksl) * 64 + lane) * 8];
      union { bf16x8 v; unsigned int w[4]; } B0, B1;
      B0.w[0] = pw[0][2*ksl][0]; B0.w[1] = pw[0][2*ksl][1];
      B0.w[2] = pw[0][2*ksl+1][0]; B0.w[3] = pw[0][2*ksl+1][1];
      B1.w[0] = pw[1][2*ksl][0]; B1.w[1] = pw[1][2*ksl][1];
      B1.w[2] = pw[1][2*ksl+1][0]; B1.w[3] = pw[1][2*ksl+1][1];
      accY0 = __builtin_amdgcn_mfma_f32_16x16x32_bf16(ya, B0.v, accY0, 0, 0, 0);
      accY1 = __builtin_amdgcn_mfma_f32_16x16x32_bf16(ya, B1.v, accY1, 0, 0, 0);
    }
  };

  // ---- software-pipelined pass chain (4 barriers) ----
  g1(IC<0>{}, Hu0);
  __syncthreads();
  g1(IC<1>{}, Hu1);          // fills Hu1 while...
  g2(IC<0>{}, Hu0);          // ...consuming Hu0
  __syncthreads();
  g1(IC<2>{}, Hu0);
  g2(IC<1>{}, Hu1);
  __syncthreads();
  g1(IC<3>{}, Hu1);
  g2(IC<2>{}, Hu0);
  __syncthreads();
  g2(IC<3>{}, Hu1);

  // ---- atomically accumulate the 12 partial planes into per-bi slab ----
  float* slab = ws + (size_t)bi * 1536;
  if (g < 3) {
    #pragma unroll
    for (int r = 0; r < 4; ++r) {
      atomicAdd(&slab[(4*g + r) * 128 + c0], accY0[r]);
      atomicAdd(&slab[(4*g + r) * 128 + c1], accY1[r]);
    }
  }
  __threadfence();
  __syncthreads();
  if (tid == 0)
    lastFlag = (atomicAdd(&cnt[bi], 1u) == NSPLIT - 1) ? 1u : 0u;
  __syncthreads();
  if (!lastFlag) return;
  __threadfence();   // acquire: make other blocks' slab adds visible

  // ---- fused final: LN + Wo + outputs (LDS reused as scratch) ----
  float* Xv = (float*)smem;            // [128]
  float* XN = (float*)(smem + 512);    // [128]
  float* PS = (float*)(smem + 1024);   // [2][128]
  float* ST = (float*)(smem + 2048);   // [2]
  if (tid < 128) {
    float acc[12];
    #pragma unroll
    for (int k = 0; k < 12; ++k) acc[k] = slab[k*128 + tid];
    const float* nvb = node_v + (size_t)bi * (3 * DD) + tid;
    float x = acc[0] + nvb[0]*acc[1] + nvb[DD]*acc[2] + nvb[2*DD]*acc[3];
    float vs = v_scale[tid], ts = t_scale[tid];
    size_t vbase = 98304 + (size_t)bi * (3 * DD) + tid;
    out[vbase]        = acc[4] * vs;
    out[vbase + DD]   = acc[5] * vs;
    out[vbase + 2*DD] = acc[6] * vs;
    size_t tbase = 393216 + (size_t)bi * (5 * DD) + tid;
    out[tbase]        = acc[7]  * ts;
    out[tbase + DD]   = acc[8]  * ts;
    out[tbase + 2*DD] = acc[9]  * ts;
    out[tbase + 3*DD] = acc[10] * ts;
    out[tbase + 4*DD] = acc[11] * ts;
    Xv[tid] = x;
  }
  __syncthreads();
  if (tid < 64) {
    float a = Xv[tid], c = Xv[tid + 64];
    float s = a + c, ss = a*a + c*c;
    #pragma unroll
    for (int off = 32; off > 0; off >>= 1) {
      s  += __shfl_down(s, off);
      ss += __shfl_down(ss, off);
    }
    if (tid == 0) {
      float mu  = s * (1.f / 128.f);
      float var = ss * (1.f / 128.f) - mu * mu;
      ST[0] = mu; ST[1] = rsqrtf(var + 1e-5f);
    }
  }
  __syncthreads();
  if (tid < 128) XN[tid] = (Xv[tid] - ST[0]) * ST[1] * ln_g[tid] + ln_b[tid];
  __syncthreads();
  {
    int dp = tid & 127, p = tid >> 7;
    float s = 0.f;
    #pragma unroll
    for (int dd = 0; dd < 64; ++dd) {
      int d = p * 64 + dd;
      s += XN[d] * Wo[d * DD + dp];
    }
    PS[p * 128 + dp] = s;
  }
  __syncthreads();
  if (tid < 128)
    out[(size_t)bi * DD + tid] = PS[tid] + PS[128 + tid] + bo[tid];
}

extern "C" void kernel_launch(void* const* d_in, const int* in_sizes, int n_in,
                              void* d_out, int out_size, void* d_ws, size_t ws_size,
                              hipStream_t stream) {
  (void)in_sizes; (void)n_in; (void)out_size; (void)ws_size;
  const float* node_s = (const float*)d_in[0];
  const float* node_v = (const float*)d_in[1];
  const float* rbf    = (const float*)d_in[3];
  const float* r_hat  = (const float*)d_in[4];
  const float* mask   = (const float*)d_in[5];
  const float* Ws1 = (const float*)d_in[6];  const float* bs1 = (const float*)d_in[7];
  const float* Ws2 = (const float*)d_in[8];  const float* bs2 = (const float*)d_in[9];
  const float* Wd1 = (const float*)d_in[10]; const float* bd1 = (const float*)d_in[11];
  const float* Wd2 = (const float*)d_in[12]; const float* bd2 = (const float*)d_in[13];
  const float* Wv1 = (const float*)d_in[14]; const float* bv1 = (const float*)d_in[15];
  const float* Wv2 = (const float*)d_in[16]; const float* bv2 = (const float*)d_in[17];
  const float* Wt1 = (const float*)d_in[18]; const float* bt1 = (const float*)d_in[19];
  const float* Wt2 = (const float*)d_in[20]; const float* bt2 = (const float*)d_in[21];
  const float* ln_g = (const float*)d_in[22]; const float* ln_b = (const float*)d_in[23];
  const float* Wo   = (const float*)d_in[24]; const float* bo   = (const float*)d_in[25];
  const float* v_scale = (const float*)d_in[26];
  const float* t_scale = (const float*)d_in[27];
  float* outp = (float*)d_out;

  // ws layout: [partials 768*1536 f32 = 4.72MB][cnt 768 u32][w1f][w2f][bcat1][bcat2]
  const size_t pbytes = 768ull * 1536 * 4;
  char* wsb = (char*)d_ws;
  float* partials = (float*)wsb;
  unsigned int* cnt = (unsigned int*)(wsb + pbytes);
  unsigned short* w1f = (unsigned short*)(wsb + pbytes + 3072);
  unsigned short* w2f = w1f + 16384;
  float* bcat1 = (float*)(w2f + 65536);
  float* bcat2 = bcat1 + 512;

  hipMemsetAsync(partials, 0, pbytes + 3072, stream);   // partials + cnt
  hipLaunchKernelGGL(cg_prep, dim3(44), dim3(256), 0, stream,
                     Ws1, Wd1, Wv1, Wt1, Ws2, Wd2, Wv2, Wt2,
                     bs1, bd1, bv1, bt1, bs2, bd2, bv2, bt2,
                     w1f, w2f, bcat1, bcat2);

  hipLaunchKernelGGL(cg_main, dim3(768 * 3), dim3(256), 0, stream,
                     node_s, node_v, rbf, r_hat, mask,
                     w1f, w2f, bcat1, bcat2,
                     ln_g, ln_b, Wo, bo, v_scale, t_scale,
                     partials, cnt, outp);
}

// Round 16
// 62.638 us; speedup vs baseline: 6.3901x; 6.3901x over previous
//
#include <hip/hip_runtime.h>
#include <hip/hip_bf16.h>

#define NB 192
#define DD 128
#define RR 32
#define RBS 40    // padded Rb row stride (ushorts)

typedef __attribute__((ext_vector_type(8))) short bf16x8;
typedef __attribute__((ext_vector_type(4))) float f32x4;

template<int M> struct IC { static constexpr int value = M; };

__device__ __forceinline__ unsigned short f2bf(float x) {
  union { __hip_bfloat16 h; unsigned short u; } c;
  c.h = __float2bfloat16(x);
  return c.u;
}
__device__ __forceinline__ unsigned int pack2bf(float a, float b) {
  union { unsigned short u[2]; unsigned int w; } r;
  r.u[0] = f2bf(a); r.u[1] = f2bf(b); return r.w;
}

// ---------------- weight fragment prep (runs every call) ----------------
__global__ __launch_bounds__(256) void cg_prep(
    const float* __restrict__ Ws1, const float* __restrict__ Wd1,
    const float* __restrict__ Wv1, const float* __restrict__ Wt1,
    const float* __restrict__ Ws2, const float* __restrict__ Wd2,
    const float* __restrict__ Wv2, const float* __restrict__ Wt2,
    const float* __restrict__ bs1, const float* __restrict__ bd1,
    const float* __restrict__ bv1, const float* __restrict__ bt1,
    const float* __restrict__ bs2, const float* __restrict__ bd2,
    const float* __restrict__ bv2, const float* __restrict__ bt2,
    unsigned short* __restrict__ w1f, unsigned short* __restrict__ w2f,
    float* __restrict__ bcat1, float* __restrict__ bcat2)
{
  const float* W1s[4] = {Ws1, Wd1, Wv1, Wt1};
  const float* W2s[4] = {Ws2, Wd2, Wv2, Wt2};
  const float* B1s[4] = {bs1, bd1, bv1, bt1};
  const float* B2s[4] = {bs2, bd2, bv2, bt2};
  int t = blockIdx.x * 256 + threadIdx.x;
  if (t < 2048) {
    int lane = t & 63, f = t >> 6;
    int mlp = f >> 3, htl = f & 7;
    int g = lane >> 4, ln = lane & 15;
    const float* W = W1s[mlp];
    union { unsigned short u[8]; uint4 d; } p;
    #pragma unroll
    for (int e = 0; e < 8; ++e)
      p.u[e] = f2bf(W[(8*g + e) * DD + htl*16 + ln]);
    *(uint4*)&w1f[t * 8] = p.d;
  } else if (t < 10240) {
    int t2 = t - 2048;
    int lane = t2 & 63, f = t2 >> 6;    // f = (mlp*4+ks)*8 + ct
    int ct = f & 7, ks = (f >> 3) & 3, mlp = f >> 5;
    int g = lane >> 4, ln = lane & 15;
    const float* W = W2s[mlp];
    union { unsigned short u[8]; uint4 d; } p;
    #pragma unroll
    for (int e = 0; e < 8; ++e)
      p.u[e] = f2bf(W[(32*ks + 8*g + e) * DD + ct*16 + ln]);
    *(uint4*)&w2f[t2 * 8] = p.d;
  } else if (t < 10752) {
    int t3 = t - 10240;
    bcat1[t3] = B1s[t3 >> 7][t3 & 127];
  } else if (t < 11264) {
    int t3 = t - 10752;
    bcat2[t3] = B2s[t3 >> 7][t3 & 127];
  }
}

// ---------------- main kernel ------------------------------------------
// JBLK=64; 4 MLP passes software-pipelined on a double-buffered Hu:
// GEMM1(k+1) overlaps GEMM2(k); 4 barriers total in the pass chain.
__global__ __launch_bounds__(256, 3) void cg_main(
    const float* __restrict__ node_s,
    const float* __restrict__ rbf, const float* __restrict__ r_hat,
    const float* __restrict__ mask,
    const unsigned short* __restrict__ w1f, const unsigned short* __restrict__ w2f,
    const float* __restrict__ bcat1, const float* __restrict__ bcat2,
    float* __restrict__ ws)
{
  constexpr int JBLK   = 64;
  constexpr int NSPLIT = NB / JBLK;   // 3
  constexpr int NT     = 4;           // j-tiles of 16
  constexpr int KSL    = 2;           // 32-j slices for Y-MFMA
  __shared__ __align__(16) char smem[49152];
  unsigned short* Rb  = (unsigned short*)smem;             // 64*40*2  = 5120
  unsigned short* Hu0 = (unsigned short*)(smem + 5120);    // 64*128*2 = 16384
  unsigned short* Hu1 = (unsigned short*)(smem + 21504);   // 64*128*2 = 16384
  float*          YYf = (float*)(smem + 37888);            // 12*64*4  = 3072
  unsigned short* YA  = (unsigned short*)(smem + 40960);   // 4*2*64*16= 8192
  // YYf planes: 0 m^2 | 1-3 m*Y1 | 4-6 m^2*Y1 | 7-11 m^2*Y2

  const int tid  = threadIdx.x;
  const int bx   = blockIdx.x;
  const int bi   = bx / NSPLIT;
  const int jq   = bx % NSPLIT;
  const int j0   = jq * JBLK;
  const int b    = bi / NB;
  const int wid  = tid >> 6;
  const int lane = tid & 63;
  const int g = lane >> 4, ln = lane & 15;

  auto haddr = [](int j, int hb) {      // hb = byte col in 256B Hu row
    return j * 128 + (((hb) ^ ((j & 7) << 4)) >> 1);
  };

  const float* nsb = node_s + (size_t)b * (NB * DD);
  const f32x4 zacc = {0.f, 0.f, 0.f, 0.f};
  const int c0 = wid * 32 + ln, c1 = c0 + 16;

  // ---- node_s rows this thread needs -> registers (issued first, used late) ----
  float nsr[4][4][2];
  {
    const float* nsp = nsb + (size_t)j0 * DD;
    #pragma unroll
    for (int mt = 0; mt < 4; ++mt)
      #pragma unroll
      for (int r = 0; r < 4; ++r) {
        int jl = mt * 16 + 4 * g + r;
        nsr[mt][r][0] = nsp[(size_t)jl * DD + c0];
        nsr[mt][r][1] = nsp[(size_t)jl * DD + c1];
      }
  }

  // ---- stage rbf -> Rb (bf16, padded stride) ----
  {
    const float4* rrow = (const float4*)(rbf + (size_t)bi * (NB * RR) + j0 * RR);
    #pragma unroll
    for (int f = tid; f < JBLK * 8; f += 256) {
      float4 v = rrow[f];
      union { unsigned short u[4]; uint2 d; } p;
      p.u[0] = f2bf(v.x); p.u[1] = f2bf(v.y); p.u[2] = f2bf(v.z); p.u[3] = f2bf(v.w);
      *(uint2*)&Rb[(f >> 3) * RBS + (f & 7) * 4] = p.d;
    }
  }
  // ---- Y tables (f32, 12 planes, m^2 folded; 3 planes per wave) ----
  {
    int j = tid & 63, grp = tid >> 6;
    int jj = j0 + j;
    const float* rh = r_hat + ((size_t)bi * NB + jj) * 3;
    float x = rh[0], y = rh[1], z = rh[2];
    float m = mask[(size_t)bi * NB + jj];
    float inv = 1.0f / (sqrtf(x*x + y*y + z*z) + 1e-12f);
    x *= inv; y *= inv; z *= inv;
    float m2 = m * m;
    float v0, v1, v2;
    if (grp == 0)      { v0 = m2;
                         v1 = 0.48860252f * m * x;
                         v2 = 0.48860252f * m * y; }
    else if (grp == 1) { v0 = 0.48860252f * m * z;
                         v1 = 0.48860252f * m2 * x;
                         v2 = 0.48860252f * m2 * y; }
    else if (grp == 2) { v0 = 0.48860252f * m2 * z;
                         v1 = 1.09254843f * m2 * x * y;
                         v2 = 1.09254843f * m2 * y * z; }
    else               { v0 = 0.31539157f * m2 * (3.f * z * z - 1.f);
                         v1 = 1.09254843f * m2 * x * z;
                         v2 = 0.54627422f * m2 * (x*x - y*y); }
    YYf[(grp*3 + 0) * JBLK + j] = v0;
    YYf[(grp*3 + 1) * JBLK + j] = v1;
    YYf[(grp*3 + 2) * JBLK + j] = v2;
  }
  __syncthreads();

  // ---- build Y A-fragments: slot(g,e) -> j = 32ksl + 16(e>>2) + 4g + (e&3) ----
  for (int s = tid; s < 4 * KSL * 64; s += 256) {
    int lane_l = s & 63, rest = s >> 6;
    int ksl = rest % KSL, m = rest / KSL;
    int gl = lane_l >> 4, lnl = lane_l & 15;
    int jb0 = 32*ksl + 4*gl;
    union { unsigned short u[8]; uint4 d; } P;
    bool ok = (m == 0 && lnl == 0) ||
              (m == 1 && lnl >= 1 && lnl <= 3) ||
              (m == 2 && lnl >= 4 && lnl <= 6) ||
              (m == 3 && lnl >= 7 && lnl <= 11);
    if (ok) {
      const float* pl = YYf + lnl * JBLK;
      float4 a = *(const float4*)(pl + jb0);
      float4 c = *(const float4*)(pl + jb0 + 16);
      P.u[0]=f2bf(a.x); P.u[1]=f2bf(a.y); P.u[2]=f2bf(a.z); P.u[3]=f2bf(a.w);
      P.u[4]=f2bf(c.x); P.u[5]=f2bf(c.y); P.u[6]=f2bf(c.z); P.u[7]=f2bf(c.w);
    } else {
      #pragma unroll
      for (int e = 0; e < 8; ++e) P.u[e] = 0;
    }
    *(uint4*)&YA[s * 8] = P.d;
  }
  __syncthreads();

  f32x4 accY0 = zacc, accY1 = zacc;   // rows = planes 0..11, cols = c0 / c1

  // ---- GEMM1 for one mode into the given Hu buffer ----
  auto g1 = [&](auto MC, unsigned short* Hu) {
    constexpr int MODE = decltype(MC)::value;
    #pragma unroll
    for (int q = 0; q < 2; ++q) {
      const int htl = wid * 2 + q;
      const int f   = MODE * 8 + htl;
      bf16x8 a1 = *(const bf16x8*)&w1f[(f * 64 + lane) * 8];
      float4 b1v = *(const float4*)(bcat1 + MODE * DD + htl*16 + 4*g);
      #pragma unroll
      for (int nt = 0; nt < NT; ++nt) {
        int j = nt * 16 + ln;
        bf16x8 bb = *(const bf16x8*)&Rb[j * RBS + 8 * g];
        f32x4 h4 = __builtin_amdgcn_mfma_f32_16x16x32_bf16(a1, bb, zacc, 0, 0, 0);
        union { unsigned short u[4]; uint2 d; } hp;
        float x0 = h4[0] + b1v.x; hp.u[0] = f2bf(x0 * __builtin_amdgcn_rcpf(1.f + __expf(-x0)));
        float x1 = h4[1] + b1v.y; hp.u[1] = f2bf(x1 * __builtin_amdgcn_rcpf(1.f + __expf(-x1)));
        float x2 = h4[2] + b1v.z; hp.u[2] = f2bf(x2 * __builtin_amdgcn_rcpf(1.f + __expf(-x2)));
        float x3 = h4[3] + b1v.w; hp.u[3] = f2bf(x3 * __builtin_amdgcn_rcpf(1.f + __expf(-x3)));
        *(uint2*)&Hu[haddr(j, htl*32 + 8*g)] = hp.d;
      }
    }
  };

  // ---- GEMM2 + epilogue + Y-MFMA for one mode from the given Hu buffer ----
  auto g2 = [&](auto MC, const unsigned short* Hu) {
    constexpr int MODE = decltype(MC)::value;
    bf16x8 Bf[4][2];
    #pragma unroll
    for (int ks = 0; ks < 4; ++ks)
      #pragma unroll
      for (int t = 0; t < 2; ++t)
        Bf[ks][t] = *(const bf16x8*)&w2f[(((MODE*4 + ks)*8 + 2*wid + t) * 64 + lane) * 8];
    float b2c0 = bcat2[MODE * DD + c0], b2c1 = bcat2[MODE * DD + c1];
    unsigned int pw[2][NT][2];
    #pragma unroll
    for (int mt = 0; mt < NT; ++mt) {
      f32x4 acc0 = zacc, acc1 = zacc;
      #pragma unroll
      for (int ks = 0; ks < 4; ++ks) {
        bf16x8 a = *(const bf16x8*)&Hu[haddr(mt*16 + ln, ks*64 + 16*g)];
        acc0 = __builtin_amdgcn_mfma_f32_16x16x32_bf16(a, Bf[ks][0], acc0, 0, 0, 0);
        acc1 = __builtin_amdgcn_mfma_f32_16x16x32_bf16(a, Bf[ks][1], acc1, 0, 0, 0);
      }
      #pragma unroll
      for (int wd = 0; wd < 2; ++wd) {
        float w00 = acc0[2*wd] + b2c0, w01 = acc0[2*wd+1] + b2c0;
        float w10 = acc1[2*wd] + b2c1, w11 = acc1[2*wd+1] + b2c1;
        float p00, p01, p10, p11;
        if constexpr (MODE == 1) {
          p00 = w00; p01 = w01; p10 = w10; p11 = w11;
        } else {
          p00 = nsr[mt][2*wd+0][0] * w00;
          p01 = nsr[mt][2*wd+1][0] * w01;
          p10 = nsr[mt][2*wd+0][1] * w10;
          p11 = nsr[mt][2*wd+1][1] * w11;
        }
        pw[0][mt][wd] = pack2bf(p00, p01);
        pw[1][mt][wd] = pack2bf(p10, p11);
      }
    }
    #pragma unroll
    for (int ksl = 0; ksl < KSL; ++ksl) {
      bf16x8 ya = *(const bf16x8*)&YA[((MODE*KSL + ksl) * 64 + lane) * 8];
      union { bf16x8 v; unsigned int w[4]; } B0, B1;
      B0.w[0] = pw[0][2*ksl][0]; B0.w[1] = pw[0][2*ksl][1];
      B0.w[2] = pw[0][2*ksl+1][0]; B0.w[3] = pw[0][2*ksl+1][1];
      B1.w[0] = pw[1][2*ksl][0]; B1.w[1] = pw[1][2*ksl][1];
      B1.w[2] = pw[1][2*ksl+1][0]; B1.w[3] = pw[1][2*ksl+1][1];
      accY0 = __builtin_amdgcn_mfma_f32_16x16x32_bf16(ya, B0.v, accY0, 0, 0, 0);
      accY1 = __builtin_amdgcn_mfma_f32_16x16x32_bf16(ya, B1.v, accY1, 0, 0, 0);
    }
  };

  // ---- software-pipelined pass chain (4 barriers) ----
  g1(IC<0>{}, Hu0);
  __syncthreads();
  g1(IC<1>{}, Hu1);          // fills Hu1 while...
  g2(IC<0>{}, Hu0);          // ...consuming Hu0
  __syncthreads();
  g1(IC<2>{}, Hu0);
  g2(IC<1>{}, Hu1);
  __syncthreads();
  g1(IC<3>{}, Hu1);
  g2(IC<2>{}, Hu0);
  __syncthreads();
  g2(IC<3>{}, Hu1);

  // ---- write 12 partial planes (rows p=4g+r, cols c0/c1) ----
  if (g < 3) {
    float* slab = ws + ((size_t)bi * NSPLIT + jq) * (12 * 128);
    #pragma unroll
    for (int r = 0; r < 4; ++r) {
      slab[(4*g + r) * 128 + c0] = accY0[r];
      slab[(4*g + r) * 128 + c1] = accY1[r];
    }
  }
}

// ---------------- final combine ----------------------------------------
// planes: 0 msg_s | 1-3 (mY1*W sums, contract with V) | 4-6 delta_v | 7-11 delta_t
template<int NSPLIT>
__global__ __launch_bounds__(256) void cg_final(
    const float* __restrict__ ws, const float* __restrict__ node_v,
    const float* __restrict__ ln_g, const float* __restrict__ ln_b,
    const float* __restrict__ Wo, const float* __restrict__ bo,
    const float* __restrict__ v_scale, const float* __restrict__ t_scale,
    float* __restrict__ out)
{
  __shared__ float Xv[128];
  __shared__ float XN[128];
  __shared__ float PS[2][128];
  __shared__ float ST[2];
  const int bi = blockIdx.x;
  const int tid = threadIdx.x;

  if (tid < 128) {
    float acc[12];
    #pragma unroll
    for (int k = 0; k < 12; ++k) acc[k] = 0.f;
    #pragma unroll
    for (int q = 0; q < NSPLIT; ++q) {
      const float* pa = ws + ((size_t)bi * NSPLIT + q) * (12 * 128);
      #pragma unroll
      for (int k = 0; k < 12; ++k) acc[k] += pa[k*128 + tid];
    }
    const float* nvb = node_v + (size_t)bi * (3 * DD) + tid;
    float x = acc[0] + nvb[0]*acc[1] + nvb[DD]*acc[2] + nvb[2*DD]*acc[3];
    float vs = v_scale[tid], ts = t_scale[tid];
    size_t vbase = 98304 + (size_t)bi * (3 * DD) + tid;
    out[vbase]        = acc[4] * vs;
    out[vbase + DD]   = acc[5] * vs;
    out[vbase + 2*DD] = acc[6] * vs;
    size_t tbase = 393216 + (size_t)bi * (5 * DD) + tid;
    out[tbase]        = acc[7]  * ts;
    out[tbase + DD]   = acc[8]  * ts;
    out[tbase + 2*DD] = acc[9]  * ts;
    out[tbase + 3*DD] = acc[10] * ts;
    out[tbase + 4*DD] = acc[11] * ts;
    Xv[tid] = x;
  }
  __syncthreads();
  if (tid < 64) {
    float a = Xv[tid], c = Xv[tid + 64];
    float s = a + c, ss = a*a + c*c;
    #pragma unroll
    for (int off = 32; off > 0; off >>= 1) {
      s  += __shfl_down(s, off);
      ss += __shfl_down(ss, off);
    }
    if (tid == 0) {
      float mu  = s * (1.f / 128.f);
      float var = ss * (1.f / 128.f) - mu * mu;
      ST[0] = mu; ST[1] = rsqrtf(var + 1e-5f);
    }
  }
  __syncthreads();
  if (tid < 128) XN[tid] = (Xv[tid] - ST[0]) * ST[1] * ln_g[tid] + ln_b[tid];
  __syncthreads();
  {
    int dp = tid & 127, p = tid >> 7;
    float s = 0.f;
    #pragma unroll
    for (int dd = 0; dd < 64; ++dd) {
      int d = p * 64 + dd;
      s += XN[d] * Wo[d * DD + dp];
    }
    PS[p][dp] = s;
  }
  __syncthreads();
  if (tid < 128)
    out[(size_t)bi * DD + tid] = PS[0][tid] + PS[1][tid] + bo[tid];
}

extern "C" void kernel_launch(void* const* d_in, const int* in_sizes, int n_in,
                              void* d_out, int out_size, void* d_ws, size_t ws_size,
                              hipStream_t stream) {
  (void)in_sizes; (void)n_in; (void)out_size; (void)ws_size;
  const float* node_s = (const float*)d_in[0];
  const float* node_v = (const float*)d_in[1];
  const float* rbf    = (const float*)d_in[3];
  const float* r_hat  = (const float*)d_in[4];
  const float* mask   = (const float*)d_in[5];
  const float* Ws1 = (const float*)d_in[6];  const float* bs1 = (const float*)d_in[7];
  const float* Ws2 = (const float*)d_in[8];  const float* bs2 = (const float*)d_in[9];
  const float* Wd1 = (const float*)d_in[10]; const float* bd1 = (const float*)d_in[11];
  const float* Wd2 = (const float*)d_in[12]; const float* bd2 = (const float*)d_in[13];
  const float* Wv1 = (const float*)d_in[14]; const float* bv1 = (const float*)d_in[15];
  const float* Wv2 = (const float*)d_in[16]; const float* bv2 = (const float*)d_in[17];
  const float* Wt1 = (const float*)d_in[18]; const float* bt1 = (const float*)d_in[19];
  const float* Wt2 = (const float*)d_in[20]; const float* bt2 = (const float*)d_in[21];
  const float* ln_g = (const float*)d_in[22]; const float* ln_b = (const float*)d_in[23];
  const float* Wo   = (const float*)d_in[24]; const float* bo   = (const float*)d_in[25];
  const float* v_scale = (const float*)d_in[26];
  const float* t_scale = (const float*)d_in[27];
  float* outp = (float*)d_out;

  // ws layout: [partials 768*3*1536 f32 = 14.16MB][w1f][w2f][bcat1][bcat2]
  const size_t pbytes = 768ull * 3 * 1536 * 4;
  char* wsb = (char*)d_ws;
  float* partials = (float*)wsb;
  unsigned short* w1f = (unsigned short*)(wsb + pbytes);
  unsigned short* w2f = w1f + 16384;
  float* bcat1 = (float*)(w2f + 65536);
  float* bcat2 = bcat1 + 512;

  hipLaunchKernelGGL(cg_prep, dim3(44), dim3(256), 0, stream,
                     Ws1, Wd1, Wv1, Wt1, Ws2, Wd2, Wv2, Wt2,
                     bs1, bd1, bv1, bt1, bs2, bd2, bv2, bt2,
                     w1f, w2f, bcat1, bcat2);

  hipLaunchKernelGGL(cg_main, dim3(768 * 3), dim3(256), 0, stream,
                     node_s, rbf, r_hat, mask,
                     w1f, w2f, bcat1, bcat2, partials);
  hipLaunchKernelGGL((cg_final<3>), dim3(768), dim3(256), 0, stream,
                     partials, node_v, ln_g, ln_b, Wo, bo, v_scale, t_scale, outp);
}

// Round 17
// 60.598 us; speedup vs baseline: 6.6052x; 1.0337x over previous
//
#include <hip/hip_runtime.h>
#include <hip/hip_bf16.h>

#define NB 192
#define DD 128
#define RR 32
#define RBS 40    // padded Rb row stride (ushorts)

typedef __attribute__((ext_vector_type(8))) short bf16x8;
typedef __attribute__((ext_vector_type(4))) float f32x4;

template<int M> struct IC { static constexpr int value = M; };

__device__ __forceinline__ unsigned short f2bf(float x) {
  union { __hip_bfloat16 h; unsigned short u; } c;
  c.h = __float2bfloat16(x);
  return c.u;
}
__device__ __forceinline__ unsigned int pack2bf(float a, float b) {
  union { unsigned short u[2]; unsigned int w; } r;
  r.u[0] = f2bf(a); r.u[1] = f2bf(b); return r.w;
}

// ---------------- weight fragment prep (runs every call) ----------------
__global__ __launch_bounds__(256) void cg_prep(
    const float* __restrict__ Ws1, const float* __restrict__ Wd1,
    const float* __restrict__ Wv1, const float* __restrict__ Wt1,
    const float* __restrict__ Ws2, const float* __restrict__ Wd2,
    const float* __restrict__ Wv2, const float* __restrict__ Wt2,
    const float* __restrict__ bs1, const float* __restrict__ bd1,
    const float* __restrict__ bv1, const float* __restrict__ bt1,
    const float* __restrict__ bs2, const float* __restrict__ bd2,
    const float* __restrict__ bv2, const float* __restrict__ bt2,
    unsigned short* __restrict__ w1f, unsigned short* __restrict__ w2f,
    float* __restrict__ bcat1, float* __restrict__ bcat2)
{
  const float* W1s[4] = {Ws1, Wd1, Wv1, Wt1};
  const float* W2s[4] = {Ws2, Wd2, Wv2, Wt2};
  const float* B1s[4] = {bs1, bd1, bv1, bt1};
  const float* B2s[4] = {bs2, bd2, bv2, bt2};
  int t = blockIdx.x * 256 + threadIdx.x;
  if (t < 2048) {
    int lane = t & 63, f = t >> 6;
    int mlp = f >> 3, htl = f & 7;
    int g = lane >> 4, ln = lane & 15;
    const float* W = W1s[mlp];
    union { unsigned short u[8]; uint4 d; } p;
    #pragma unroll
    for (int e = 0; e < 8; ++e)
      p.u[e] = f2bf(W[(8*g + e) * DD + htl*16 + ln]);
    *(uint4*)&w1f[t * 8] = p.d;
  } else if (t < 10240) {
    int t2 = t - 2048;
    int lane = t2 & 63, f = t2 >> 6;    // f = (mlp*4+ks)*8 + ct
    int ct = f & 7, ks = (f >> 3) & 3, mlp = f >> 5;
    int g = lane >> 4, ln = lane & 15;
    const float* W = W2s[mlp];
    union { unsigned short u[8]; uint4 d; } p;
    #pragma unroll
    for (int e = 0; e < 8; ++e)
      p.u[e] = f2bf(W[(32*ks + 8*g + e) * DD + ct*16 + ln]);
    *(uint4*)&w2f[t2 * 8] = p.d;
  } else if (t < 10752) {
    int t3 = t - 10240;
    bcat1[t3] = B1s[t3 >> 7][t3 & 127];
  } else if (t < 11264) {
    int t3 = t - 10752;
    bcat2[t3] = B2s[t3 >> 7][t3 & 127];
  }
}

// ---------------- main kernel ------------------------------------------
// JBLK=64; 4 MLP passes software-pipelined on a double-buffered Hu
// (4 barriers in the pass chain). 40KB LDS (4 blocks/CU): the 8KB tail
// region holds {Rb+YYf} during the prologue, then is reused for YA
// (Rb fragments hoisted to registers; YA built through registers).
__global__ __launch_bounds__(256, 4) void cg_main(
    const float* __restrict__ node_s,
    const float* __restrict__ rbf, const float* __restrict__ r_hat,
    const float* __restrict__ mask,
    const unsigned short* __restrict__ w1f, const unsigned short* __restrict__ w2f,
    const float* __restrict__ bcat1, const float* __restrict__ bcat2,
    float* __restrict__ ws)
{
  constexpr int JBLK   = 64;
  constexpr int NSPLIT = NB / JBLK;   // 3
  constexpr int NT     = 4;           // j-tiles of 16
  constexpr int KSL    = 2;           // 32-j slices for Y-MFMA
  __shared__ __align__(16) char smem[40960];
  unsigned short* Hu0 = (unsigned short*)smem;             // 64*128*2 = 16384
  unsigned short* Hu1 = (unsigned short*)(smem + 16384);   // 64*128*2 = 16384
  unsigned short* Rb  = (unsigned short*)(smem + 32768);   // 64*40*2  = 5120 (prologue)
  float*          YYf = (float*)(smem + 37888);            // 12*64*4  = 3072 (prologue)
  unsigned short* YA  = (unsigned short*)(smem + 32768);   // 8192 (after prologue)
  // YYf planes: 0 m^2 | 1-3 m*Y1 | 4-6 m^2*Y1 | 7-11 m^2*Y2

  const int tid  = threadIdx.x;
  const int bx   = blockIdx.x;
  const int bi   = bx / NSPLIT;
  const int jq   = bx % NSPLIT;
  const int j0   = jq * JBLK;
  const int b    = bi / NB;
  const int wid  = tid >> 6;
  const int lane = tid & 63;
  const int g = lane >> 4, ln = lane & 15;

  auto haddr = [](int j, int hb) {      // hb = byte col in 256B Hu row
    return j * 128 + (((hb) ^ ((j & 7) << 4)) >> 1);
  };

  const float* nsb = node_s + (size_t)b * (NB * DD);
  const f32x4 zacc = {0.f, 0.f, 0.f, 0.f};
  const int c0 = wid * 32 + ln, c1 = c0 + 16;

  // ---- node_s rows this thread needs -> registers (issued first, used late) ----
  float nsr[4][4][2];
  {
    const float* nsp = nsb + (size_t)j0 * DD;
    #pragma unroll
    for (int mt = 0; mt < 4; ++mt)
      #pragma unroll
      for (int r = 0; r < 4; ++r) {
        int jl = mt * 16 + 4 * g + r;
        nsr[mt][r][0] = nsp[(size_t)jl * DD + c0];
        nsr[mt][r][1] = nsp[(size_t)jl * DD + c1];
      }
  }

  // ---- stage rbf -> Rb (bf16, padded stride) ----
  {
    const float4* rrow = (const float4*)(rbf + (size_t)bi * (NB * RR) + j0 * RR);
    #pragma unroll
    for (int f = tid; f < JBLK * 8; f += 256) {
      float4 v = rrow[f];
      union { unsigned short u[4]; uint2 d; } p;
      p.u[0] = f2bf(v.x); p.u[1] = f2bf(v.y); p.u[2] = f2bf(v.z); p.u[3] = f2bf(v.w);
      *(uint2*)&Rb[(f >> 3) * RBS + (f & 7) * 4] = p.d;
    }
  }
  // ---- Y tables (f32, 12 planes, m^2 folded; 3 planes per wave) ----
  {
    int j = tid & 63, grp = tid >> 6;
    int jj = j0 + j;
    const float* rh = r_hat + ((size_t)bi * NB + jj) * 3;
    float x = rh[0], y = rh[1], z = rh[2];
    float m = mask[(size_t)bi * NB + jj];
    float inv = 1.0f / (sqrtf(x*x + y*y + z*z) + 1e-12f);
    x *= inv; y *= inv; z *= inv;
    float m2 = m * m;
    float v0, v1, v2;
    if (grp == 0)      { v0 = m2;
                         v1 = 0.48860252f * m * x;
                         v2 = 0.48860252f * m * y; }
    else if (grp == 1) { v0 = 0.48860252f * m * z;
                         v1 = 0.48860252f * m2 * x;
                         v2 = 0.48860252f * m2 * y; }
    else if (grp == 2) { v0 = 0.48860252f * m2 * z;
                         v1 = 1.09254843f * m2 * x * y;
                         v2 = 1.09254843f * m2 * y * z; }
    else               { v0 = 0.31539157f * m2 * (3.f * z * z - 1.f);
                         v1 = 1.09254843f * m2 * x * z;
                         v2 = 0.54627422f * m2 * (x*x - y*y); }
    YYf[(grp*3 + 0) * JBLK + j] = v0;
    YYf[(grp*3 + 1) * JBLK + j] = v1;
    YYf[(grp*3 + 2) * JBLK + j] = v2;
  }
  __syncthreads();

  // ---- hoist pass-invariant rbf B-fragments into registers ----
  bf16x8 bbr[NT];
  #pragma unroll
  for (int nt = 0; nt < NT; ++nt)
    bbr[nt] = *(const bf16x8*)&Rb[(nt * 16 + ln) * RBS + 8 * g];

  // ---- compute Y A-fragments in REGISTERS (region still holds Rb/YYf) ----
  // slot(g,e) -> j = 32ksl + 16(e>>2) + 4g + (e&3)
  auto yafrag = [&](int s) -> uint4 {
    int lane_l = s & 63, rest = s >> 6;
    int ksl = rest % KSL, m = rest / KSL;
    int gl = lane_l >> 4, lnl = lane_l & 15;
    int jb0 = 32*ksl + 4*gl;
    union { unsigned short u[8]; uint4 d; } P;
    bool ok = (m == 0 && lnl == 0) ||
              (m == 1 && lnl >= 1 && lnl <= 3) ||
              (m == 2 && lnl >= 4 && lnl <= 6) ||
              (m == 3 && lnl >= 7 && lnl <= 11);
    if (ok) {
      const float* pl = YYf + lnl * JBLK;
      float4 a = *(const float4*)(pl + jb0);
      float4 c = *(const float4*)(pl + jb0 + 16);
      P.u[0]=f2bf(a.x); P.u[1]=f2bf(a.y); P.u[2]=f2bf(a.z); P.u[3]=f2bf(a.w);
      P.u[4]=f2bf(c.x); P.u[5]=f2bf(c.y); P.u[6]=f2bf(c.z); P.u[7]=f2bf(c.w);
    } else {
      #pragma unroll
      for (int e = 0; e < 8; ++e) P.u[e] = 0;
    }
    return P.d;
  };
  uint4 YP0 = yafrag(tid);          // 4*KSL*64 = 512 slots, 2 per thread
  uint4 YP1 = yafrag(tid + 256);
  __syncthreads();                   // all Rb/YYf reads complete
  *(uint4*)&YA[tid * 8]         = YP0;
  *(uint4*)&YA[(tid + 256) * 8] = YP1;
  __syncthreads();                   // YA visible to all

  f32x4 accY0 = zacc, accY1 = zacc;  // rows = planes 0..11, cols = c0 / c1

  // ---- GEMM1 for one mode into the given Hu buffer ----
  auto g1 = [&](auto MC, unsigned short* Hu) {
    constexpr int MODE = decltype(MC)::value;
    #pragma unroll
    for (int q = 0; q < 2; ++q) {
      const int htl = wid * 2 + q;
      const int f   = MODE * 8 + htl;
      bf16x8 a1 = *(const bf16x8*)&w1f[(f * 64 + lane) * 8];
      float4 b1v = *(const float4*)(bcat1 + MODE * DD + htl*16 + 4*g);
      #pragma unroll
      for (int nt = 0; nt < NT; ++nt) {
        int j = nt * 16 + ln;
        f32x4 h4 = __builtin_amdgcn_mfma_f32_16x16x32_bf16(a1, bbr[nt], zacc, 0, 0, 0);
        union { unsigned short u[4]; uint2 d; } hp;
        float x0 = h4[0] + b1v.x; hp.u[0] = f2bf(x0 * __builtin_amdgcn_rcpf(1.f + __expf(-x0)));
        float x1 = h4[1] + b1v.y; hp.u[1] = f2bf(x1 * __builtin_amdgcn_rcpf(1.f + __expf(-x1)));
        float x2 = h4[2] + b1v.z; hp.u[2] = f2bf(x2 * __builtin_amdgcn_rcpf(1.f + __expf(-x2)));
        float x3 = h4[3] + b1v.w; hp.u[3] = f2bf(x3 * __builtin_amdgcn_rcpf(1.f + __expf(-x3)));
        *(uint2*)&Hu[haddr(j, htl*32 + 8*g)] = hp.d;
      }
    }
  };

  // ---- GEMM2 + epilogue + Y-MFMA for one mode from the given Hu buffer ----
  auto g2 = [&](auto MC, const unsigned short* Hu) {
    constexpr int MODE = decltype(MC)::value;
    bf16x8 Bf[4][2];
    #pragma unroll
    for (int ks = 0; ks < 4; ++ks)
      #pragma unroll
      for (int t = 0; t < 2; ++t)
        Bf[ks][t] = *(const bf16x8*)&w2f[(((MODE*4 + ks)*8 + 2*wid + t) * 64 + lane) * 8];
    float b2c0 = bcat2[MODE * DD + c0], b2c1 = bcat2[MODE * DD + c1];
    unsigned int pw[2][NT][2];
    #pragma unroll
    for (int mt = 0; mt < NT; ++mt) {
      f32x4 acc0 = zacc, acc1 = zacc;
      #pragma unroll
      for (int ks = 0; ks < 4; ++ks) {
        bf16x8 a = *(const bf16x8*)&Hu[haddr(mt*16 + ln, ks*64 + 16*g)];
        acc0 = __builtin_amdgcn_mfma_f32_16x16x32_bf16(a, Bf[ks][0], acc0, 0, 0, 0);
        acc1 = __builtin_amdgcn_mfma_f32_16x16x32_bf16(a, Bf[ks][1], acc1, 0, 0, 0);
      }
      #pragma unroll
      for (int wd = 0; wd < 2; ++wd) {
        float w00 = acc0[2*wd] + b2c0, w01 = acc0[2*wd+1] + b2c0;
        float w10 = acc1[2*wd] + b2c1, w11 = acc1[2*wd+1] + b2c1;
        float p00, p01, p10, p11;
        if constexpr (MODE == 1) {
          p00 = w00; p01 = w01; p10 = w10; p11 = w11;
        } else {
          p00 = nsr[mt][2*wd+0][0] * w00;
          p01 = nsr[mt][2*wd+1][0] * w01;
          p10 = nsr[mt][2*wd+0][1] * w10;
          p11 = nsr[mt][2*wd+1][1] * w11;
        }
        pw[0][mt][wd] = pack2bf(p00, p01);
        pw[1][mt][wd] = pack2bf(p10, p11);
      }
    }
    #pragma unroll
    for (int ksl = 0; ksl < KSL; ++ksl) {
      bf16x8 ya = *(const bf16x8*)&YA[((MODE*KSL + ksl) * 64 + lane) * 8];
      union { bf16x8 v; unsigned int w[4]; } B0, B1;
      B0.w[0] = pw[0][2*ksl][0]; B0.w[1] = pw[0][2*ksl][1];
      B0.w[2] = pw[0][2*ksl+1][0]; B0.w[3] = pw[0][2*ksl+1][1];
      B1.w[0] = pw[1][2*ksl][0]; B1.w[1] = pw[1][2*ksl][1];
      B1.w[2] = pw[1][2*ksl+1][0]; B1.w[3] = pw[1][2*ksl+1][1];
      accY0 = __builtin_amdgcn_mfma_f32_16x16x32_bf16(ya, B0.v, accY0, 0, 0, 0);
      accY1 = __builtin_amdgcn_mfma_f32_16x16x32_bf16(ya, B1.v, accY1, 0, 0, 0);
    }
  };

  // ---- software-pipelined pass chain (4 barriers) ----
  g1(IC<0>{}, Hu0);
  __syncthreads();
  g1(IC<1>{}, Hu1);          // fills Hu1 while...
  g2(IC<0>{}, Hu0);          // ...consuming Hu0
  __syncthreads();
  g1(IC<2>{}, Hu0);
  g2(IC<1>{}, Hu1);
  __syncthreads();
  g1(IC<3>{}, Hu1);
  g2(IC<2>{}, Hu0);
  __syncthreads();
  g2(IC<3>{}, Hu1);

  // ---- write 12 partial planes (rows p=4g+r, cols c0/c1) ----
  if (g < 3) {
    float* slab = ws + ((size_t)bi * NSPLIT + jq) * (12 * 128);
    #pragma unroll
    for (int r = 0; r < 4; ++r) {
      slab[(4*g + r) * 128 + c0] = accY0[r];
      slab[(4*g + r) * 128 + c1] = accY1[r];
    }
  }
}

// ---------------- final combine ----------------------------------------
// planes: 0 msg_s | 1-3 (mY1*W sums, contract with V) | 4-6 delta_v | 7-11 delta_t
template<int NSPLIT>
__global__ __launch_bounds__(256) void cg_final(
    const float* __restrict__ ws, const float* __restrict__ node_v,
    const float* __restrict__ ln_g, const float* __restrict__ ln_b,
    const float* __restrict__ Wo, const float* __restrict__ bo,
    const float* __restrict__ v_scale, const float* __restrict__ t_scale,
    float* __restrict__ out)
{
  __shared__ float Xv[128];
  __shared__ float XN[128];
  __shared__ float PS[2][128];
  __shared__ float ST[2];
  const int bi = blockIdx.x;
  const int tid = threadIdx.x;

  if (tid < 128) {
    float acc[12];
    #pragma unroll
    for (int k = 0; k < 12; ++k) acc[k] = 0.f;
    #pragma unroll
    for (int q = 0; q < NSPLIT; ++q) {
      const float* pa = ws + ((size_t)bi * NSPLIT + q) * (12 * 128);
      #pragma unroll
      for (int k = 0; k < 12; ++k) acc[k] += pa[k*128 + tid];
    }
    const float* nvb = node_v + (size_t)bi * (3 * DD) + tid;
    float x = acc[0] + nvb[0]*acc[1] + nvb[DD]*acc[2] + nvb[2*DD]*acc[3];
    float vs = v_scale[tid], ts = t_scale[tid];
    size_t vbase = 98304 + (size_t)bi * (3 * DD) + tid;
    out[vbase]        = acc[4] * vs;
    out[vbase + DD]   = acc[5] * vs;
    out[vbase + 2*DD] = acc[6] * vs;
    size_t tbase = 393216 + (size_t)bi * (5 * DD) + tid;
    out[tbase]        = acc[7]  * ts;
    out[tbase + DD]   = acc[8]  * ts;
    out[tbase + 2*DD] = acc[9]  * ts;
    out[tbase + 3*DD] = acc[10] * ts;
    out[tbase + 4*DD] = acc[11] * ts;
    Xv[tid] = x;
  }
  __syncthreads();
  if (tid < 64) {
    float a = Xv[tid], c = Xv[tid + 64];
    float s = a + c, ss = a*a + c*c;
    #pragma unroll
    for (int off = 32; off > 0; off >>= 1) {
      s  += __shfl_down(s, off);
      ss += __shfl_down(ss, off);
    }
    if (tid == 0) {
      float mu  = s * (1.f / 128.f);
      float var = ss * (1.f / 128.f) - mu * mu;
      ST[0] = mu; ST[1] = rsqrtf(var + 1e-5f);
    }
  }
  __syncthreads();
  if (tid < 128) XN[tid] = (Xv[tid] - ST[0]) * ST[1] * ln_g[tid] + ln_b[tid];
  __syncthreads();
  {
    int dp = tid & 127, p = tid >> 7;
    float s = 0.f;
    #pragma unroll
    for (int dd = 0; dd < 64; ++dd) {
      int d = p * 64 + dd;
      s += XN[d] * Wo[d * DD + dp];
    }
    PS[p][dp] = s;
  }
  __syncthreads();
  if (tid < 128)
    out[(size_t)bi * DD + tid] = PS[0][tid] + PS[1][tid] + bo[tid];
}

extern "C" void kernel_launch(void* const* d_in, const int* in_sizes, int n_in,
                              void* d_out, int out_size, void* d_ws, size_t ws_size,
                              hipStream_t stream) {
  (void)in_sizes; (void)n_in; (void)out_size; (void)ws_size;
  const float* node_s = (const float*)d_in[0];
  const float* node_v = (const float*)d_in[1];
  const float* rbf    = (const float*)d_in[3];
  const float* r_hat  = (const float*)d_in[4];
  const float* mask   = (const float*)d_in[5];
  const float* Ws1 = (const float*)d_in[6];  const float* bs1 = (const float*)d_in[7];
  const float* Ws2 = (const float*)d_in[8];  const float* bs2 = (const float*)d_in[9];
  const float* Wd1 = (const float*)d_in[10]; const float* bd1 = (const float*)d_in[11];
  const float* Wd2 = (const float*)d_in[12]; const float* bd2 = (const float*)d_in[13];
  const float* Wv1 = (const float*)d_in[14]; const float* bv1 = (const float*)d_in[15];
  const float* Wv2 = (const float*)d_in[16]; const float* bv2 = (const float*)d_in[17];
  const float* Wt1 = (const float*)d_in[18]; const float* bt1 = (const float*)d_in[19];
  const float* Wt2 = (const float*)d_in[20]; const float* bt2 = (const float*)d_in[21];
  const float* ln_g = (const float*)d_in[22]; const float* ln_b = (const float*)d_in[23];
  const float* Wo   = (const float*)d_in[24]; const float* bo   = (const float*)d_in[25];
  const float* v_scale = (const float*)d_in[26];
  const float* t_scale = (const float*)d_in[27];
  float* outp = (float*)d_out;

  // ws layout: [partials 768*3*1536 f32 = 14.16MB][w1f][w2f][bcat1][bcat2]
  const size_t pbytes = 768ull * 3 * 1536 * 4;
  char* wsb = (char*)d_ws;
  float* partials = (float*)wsb;
  unsigned short* w1f = (unsigned short*)(wsb + pbytes);
  unsigned short* w2f = w1f + 16384;
  float* bcat1 = (float*)(w2f + 65536);
  float* bcat2 = bcat1 + 512;

  hipLaunchKernelGGL(cg_prep, dim3(44), dim3(256), 0, stream,
                     Ws1, Wd1, Wv1, Wt1, Ws2, Wd2, Wv2, Wt2,
                     bs1, bd1, bv1, bt1, bs2, bd2, bv2, bt2,
                     w1f, w2f, bcat1, bcat2);

  hipLaunchKernelGGL(cg_main, dim3(768 * 3), dim3(256), 0, stream,
                     node_s, rbf, r_hat, mask,
                     w1f, w2f, bcat1, bcat2, partials);
  hipLaunchKernelGGL((cg_final<3>), dim3(768), dim3(256), 0, stream,
                     partials, node_v, ln_g, ln_b, Wo, bo, v_scale, t_scale, outp);
}